// Round 1
// baseline (1636.778 us; speedup 1.0000x reference)
//
#include <hip/hip_runtime.h>
#include <math.h>

#define D_MODEL 1024
#define N_HEADS 16
#define HEAD_DIM 64
#define D_FF 4096
#define BATCH 128
#define MEM_LEN 1024

// ---------------- workspace layout (float offsets) ----------------
#define Q_OFF    0u          // 128*1024
#define SC_OFF   131072u     // 128*16*1024 scores/attn
#define PART_OFF 2228224u    // 128*16*1024 PV partials
#define AO_OFF   4325376u    // 128*1024
#define Y_OFF    4456448u    // 128*1024
#define H_OFF    4587520u    // 128*1024
#define T_OFF    4718592u    // 128*4096
#define F_OFF    5242880u    // 128*1024

// ---------------- generic tiled f32 GEMM: C = act(alpha*(A@B + bias)) ----
// A: MxK row-major, B: KxN row-major, bias: N, C: MxN
template<bool RELU>
__global__ __launch_bounds__(256) void gemm_bias(
    const float* __restrict__ A, const float* __restrict__ B,
    const float* __restrict__ bias, float* __restrict__ C,
    int M, int N, int K, float alpha)
{
    constexpr int BM = 64, BN = 64, BK = 16;
    __shared__ __align__(16) float As[BK][BM];
    __shared__ __align__(16) float Bs[BK][BN];
    const int tid = threadIdx.x;
    const int tx = tid & 15;       // output col group
    const int ty = tid >> 4;       // output row group
    const int bm = blockIdx.y * BM;
    const int bn = blockIdx.x * BN;
    // A-tile load mapping: 64 rows x 16 k, 4 consecutive k per thread
    const int arow = tid >> 2;
    const int acol = (tid & 3) << 2;
    // B-tile load mapping: 16 k x 64 cols, float4 per thread
    const int brow = tid >> 4;
    const int bcol = (tid & 15) << 2;

    float acc[4][4] = {};

    for (int k0 = 0; k0 < K; k0 += BK) {
        float4 av = *(const float4*)(A + (size_t)(bm + arow) * K + k0 + acol);
        As[acol + 0][arow] = av.x;
        As[acol + 1][arow] = av.y;
        As[acol + 2][arow] = av.z;
        As[acol + 3][arow] = av.w;
        *(float4*)&Bs[brow][bcol] =
            *(const float4*)(B + (size_t)(k0 + brow) * N + bn + bcol);
        __syncthreads();
#pragma unroll
        for (int k = 0; k < BK; ++k) {
            float4 a = *(float4*)&As[k][ty << 2];
            float4 b = *(float4*)&Bs[k][tx << 2];
            acc[0][0] += a.x * b.x; acc[0][1] += a.x * b.y;
            acc[0][2] += a.x * b.z; acc[0][3] += a.x * b.w;
            acc[1][0] += a.y * b.x; acc[1][1] += a.y * b.y;
            acc[1][2] += a.y * b.z; acc[1][3] += a.y * b.w;
            acc[2][0] += a.z * b.x; acc[2][1] += a.z * b.y;
            acc[2][2] += a.z * b.z; acc[2][3] += a.z * b.w;
            acc[3][0] += a.w * b.x; acc[3][1] += a.w * b.y;
            acc[3][2] += a.w * b.z; acc[3][3] += a.w * b.w;
        }
        __syncthreads();
    }

    float4 bv = *(const float4*)(bias + bn + (tx << 2));
#pragma unroll
    for (int i = 0; i < 4; ++i) {
        float4 o;
        o.x = alpha * (acc[i][0] + bv.x);
        o.y = alpha * (acc[i][1] + bv.y);
        o.z = alpha * (acc[i][2] + bv.z);
        o.w = alpha * (acc[i][3] + bv.w);
        if (RELU) {
            o.x = fmaxf(o.x, 0.f); o.y = fmaxf(o.y, 0.f);
            o.z = fmaxf(o.z, 0.f); o.w = fmaxf(o.w, 0.f);
        }
        *(float4*)(C + (size_t)(bm + (ty << 2) + i) * N + bn + (tx << 2)) = o;
    }
}

// ---------------- scores: (B,16,M) = q . k + alibi ----------------
// grid (BATCH, MEM_LEN/64), 256 threads; thread t owns cols t*4..t*4+3,
// head = t/16 (16 threads x 4 floats = 64 = HEAD_DIM).
__global__ __launch_bounds__(256) void scores_kernel(
    const float* __restrict__ q,       // (B,1024) pre-scaled by 1/8
    const float* __restrict__ Kmem,    // (B, M, 1024)
    const float* __restrict__ alibi,   // (16, 1024)
    float* __restrict__ scores)        // (B, 16, M)
{
    const int b = blockIdx.x;
    const int mc = blockIdx.y;
    const int t = threadIdx.x;
    const int h = t >> 4;
    const float4 qv = *(const float4*)(q + (size_t)b * D_MODEL + (t << 2));
    const float* krow = Kmem + ((size_t)b * MEM_LEN + mc * 64) * D_MODEL;
#pragma unroll 4
    for (int m = 0; m < 64; ++m) {
        float4 kv = *(const float4*)(krow + (size_t)m * D_MODEL + (t << 2));
        float p = qv.x * kv.x + qv.y * kv.y + qv.z * kv.z + qv.w * kv.w;
        p += __shfl_xor(p, 1);
        p += __shfl_xor(p, 2);
        p += __shfl_xor(p, 4);
        p += __shfl_xor(p, 8);
        if ((t & 15) == 0) {
            int mm = mc * 64 + m;
            scores[((size_t)b * N_HEADS + h) * MEM_LEN + mm] =
                p + alibi[h * MEM_LEN + mm];
        }
    }
}

// ---------------- softmax over last dim (rows of 1024) ----------------
__global__ __launch_bounds__(256) void softmax_kernel(float* __restrict__ s)
{
    const int row = blockIdx.x;     // b*16+h
    const int t = threadIdx.x;
    __shared__ float redm[4];
    __shared__ float reds[4];
    float4 v = *(float4*)(s + (size_t)row * MEM_LEN + (t << 2));
    float mx = fmaxf(fmaxf(v.x, v.y), fmaxf(v.z, v.w));
#pragma unroll
    for (int off = 32; off >= 1; off >>= 1) mx = fmaxf(mx, __shfl_xor(mx, off));
    if ((t & 63) == 0) redm[t >> 6] = mx;
    __syncthreads();
    mx = fmaxf(fmaxf(redm[0], redm[1]), fmaxf(redm[2], redm[3]));
    v.x = __expf(v.x - mx); v.y = __expf(v.y - mx);
    v.z = __expf(v.z - mx); v.w = __expf(v.w - mx);
    float sum = v.x + v.y + v.z + v.w;
#pragma unroll
    for (int off = 32; off >= 1; off >>= 1) sum += __shfl_xor(sum, off);
    if ((t & 63) == 0) reds[t >> 6] = sum;
    __syncthreads();
    float inv = 1.0f / (reds[0] + reds[1] + reds[2] + reds[3]);
    v.x *= inv; v.y *= inv; v.z *= inv; v.w *= inv;
    *(float4*)(s + (size_t)row * MEM_LEN + (t << 2)) = v;
}

// ---------------- PV partials: part(b,chunk,:) = sum_m attn*v ----------
__global__ __launch_bounds__(256) void pv_kernel(
    const float* __restrict__ attn,   // (B,16,M)
    const float* __restrict__ V,      // (B, M, 1024)
    float* __restrict__ part)         // (B, 16, 1024)
{
    const int b = blockIdx.x;
    const int mc = blockIdx.y;
    const int t = threadIdx.x;
    const int h = t >> 4;
    const float* vrow = V + ((size_t)b * MEM_LEN + mc * 64) * D_MODEL;
    const float* aw = attn + ((size_t)b * N_HEADS + h) * MEM_LEN + mc * 64;
    float4 acc = {0.f, 0.f, 0.f, 0.f};
#pragma unroll 4
    for (int m = 0; m < 64; ++m) {
        float4 vv = *(const float4*)(vrow + (size_t)m * D_MODEL + (t << 2));
        float w = aw[m];
        acc.x += vv.x * w; acc.y += vv.y * w;
        acc.z += vv.z * w; acc.w += vv.w * w;
    }
    *(float4*)(part + ((size_t)b * 16 + mc) * D_MODEL + (t << 2)) = acc;
}

// ---------------- reduce 16 partials -> attn_out ----------------
__global__ __launch_bounds__(256) void reduce_kernel(
    const float* __restrict__ part, float* __restrict__ ao)
{
    const int b = blockIdx.x;
    const int t = threadIdx.x;
    float4 s = {0.f, 0.f, 0.f, 0.f};
#pragma unroll
    for (int c = 0; c < 16; ++c) {
        float4 p = *(const float4*)(part + ((size_t)b * 16 + c) * D_MODEL + (t << 2));
        s.x += p.x; s.y += p.y; s.z += p.z; s.w += p.w;
    }
    *(float4*)(ao + (size_t)b * D_MODEL + (t << 2)) = s;
}

// ---------------- residual + layernorm: out = LN(A + B) ----------------
__global__ __launch_bounds__(256) void add_ln_kernel(
    const float* __restrict__ A, const float* __restrict__ Bv,
    const float* __restrict__ g, const float* __restrict__ be,
    float* __restrict__ out)
{
    const int b = blockIdx.x;
    const int t = threadIdx.x;
    __shared__ float red1[4];
    __shared__ float red2[4];
    float4 xa = *(const float4*)(A + (size_t)b * D_MODEL + (t << 2));
    float4 xb = *(const float4*)(Bv + (size_t)b * D_MODEL + (t << 2));
    float4 x = {xa.x + xb.x, xa.y + xb.y, xa.z + xb.z, xa.w + xb.w};
    float s = x.x + x.y + x.z + x.w;
#pragma unroll
    for (int off = 32; off >= 1; off >>= 1) s += __shfl_xor(s, off);
    if ((t & 63) == 0) red1[t >> 6] = s;
    __syncthreads();
    float mu = (red1[0] + red1[1] + red1[2] + red1[3]) * (1.0f / 1024.0f);
    float4 d = {x.x - mu, x.y - mu, x.z - mu, x.w - mu};
    float s2 = d.x * d.x + d.y * d.y + d.z * d.z + d.w * d.w;
#pragma unroll
    for (int off = 32; off >= 1; off >>= 1) s2 += __shfl_xor(s2, off);
    if ((t & 63) == 0) red2[t >> 6] = s2;
    __syncthreads();
    float var = (red2[0] + red2[1] + red2[2] + red2[3]) * (1.0f / 1024.0f);
    float r = rsqrtf(var + 1e-5f);
    float4 g4 = *(const float4*)(g + (t << 2));
    float4 b4 = *(const float4*)(be + (t << 2));
    float4 o = {d.x * r * g4.x + b4.x, d.y * r * g4.y + b4.y,
                d.z * r * g4.z + b4.z, d.w * r * g4.w + b4.w};
    *(float4*)(out + (size_t)b * D_MODEL + (t << 2)) = o;
}

extern "C" void kernel_launch(void* const* d_in, const int* in_sizes, int n_in,
                              void* d_out, int out_size, void* d_ws, size_t ws_size,
                              hipStream_t stream)
{
    const float* x      = (const float*)d_in[0];
    const float* Kmem   = (const float*)d_in[1];
    const float* Vmem   = (const float*)d_in[2];
    const float* alibi  = (const float*)d_in[3];
    const float* Wq     = (const float*)d_in[4];
    const float* bq     = (const float*)d_in[5];
    const float* Wo     = (const float*)d_in[6];
    const float* bo     = (const float*)d_in[7];
    const float* W1     = (const float*)d_in[8];
    const float* b1     = (const float*)d_in[9];
    const float* W2     = (const float*)d_in[10];
    const float* b2     = (const float*)d_in[11];
    const float* g1     = (const float*)d_in[12];
    const float* be1    = (const float*)d_in[13];
    const float* g2     = (const float*)d_in[14];
    const float* be2    = (const float*)d_in[15];
    float* out = (float*)d_out;
    float* ws  = (float*)d_ws;

    float* q     = ws + Q_OFF;
    float* sc    = ws + SC_OFF;
    float* part  = ws + PART_OFF;
    float* ao    = ws + AO_OFF;
    float* y     = ws + Y_OFF;
    float* h     = ws + H_OFF;
    float* tbuf  = ws + T_OFF;
    float* f     = ws + F_OFF;

    const float scale = 0.125f;   // 1/sqrt(64)

    // 1. q = (x @ Wq + bq) * scale
    gemm_bias<false><<<dim3(D_MODEL / 64, BATCH / 64), 256, 0, stream>>>(
        x, Wq, bq, q, BATCH, D_MODEL, D_MODEL, scale);
    // 2. scores = q . k + alibi
    scores_kernel<<<dim3(BATCH, MEM_LEN / 64), 256, 0, stream>>>(q, Kmem, alibi, sc);
    // 3. softmax rows
    softmax_kernel<<<BATCH * N_HEADS, 256, 0, stream>>>(sc);
    // 4. PV partials
    pv_kernel<<<dim3(BATCH, MEM_LEN / 64), 256, 0, stream>>>(sc, Vmem, part);
    // 5. reduce partials
    reduce_kernel<<<BATCH, 256, 0, stream>>>(part, ao);
    // 6. o-proj
    gemm_bias<false><<<dim3(D_MODEL / 64, BATCH / 64), 256, 0, stream>>>(
        ao, Wo, bo, y, BATCH, D_MODEL, D_MODEL, 1.0f);
    // 7. h = LN(x + y)
    add_ln_kernel<<<BATCH, 256, 0, stream>>>(x, y, g1, be1, h);
    // 8. t = relu(h @ W1 + b1)
    gemm_bias<true><<<dim3(D_FF / 64, BATCH / 64), 256, 0, stream>>>(
        h, W1, b1, tbuf, BATCH, D_FF, D_MODEL, 1.0f);
    // 9. f = t @ W2 + b2
    gemm_bias<false><<<dim3(D_MODEL / 64, BATCH / 64), 256, 0, stream>>>(
        tbuf, W2, b2, f, BATCH, D_MODEL, D_FF, 1.0f);
    // 10. out = LN(h + f)
    add_ln_kernel<<<BATCH, 256, 0, stream>>>(h, f, g2, be2, out);
}